// Round 15
// baseline (380.629 us; speedup 1.0000x reference)
//
#include <hip/hip_runtime.h>
#include <math.h>

// Problem constants
#define DIMD 1024
#define NHD  16
#define HDD  64
#define BBB  4
#define SSS  2048
#define MMM  (BBB*SSS)   // 8192 rows

typedef __bf16 bf16;
typedef __bf16 bf16x8 __attribute__((ext_vector_type(8)));
typedef __bf16 bf16x4 __attribute__((ext_vector_type(4)));
typedef float  f32x4  __attribute__((ext_vector_type(4)));

// ---------------- helpers ----------------

__device__ __forceinline__ void gld16(const void* g, void* l) {
  __builtin_amdgcn_global_load_lds((const __attribute__((address_space(1))) void*)g,
                                   (__attribute__((address_space(3))) void*)l,
                                   16, 0, 0);
}

__device__ __forceinline__ f32x4 mfma_bf16(bf16x8 a, bf16x8 b, f32x4 c) {
  return __builtin_amdgcn_mfma_f32_16x16x32_bf16(a, b, c, 0, 0, 0);
}

// tanh-form GELU via sigmoid identity: 0.5x(1+tanh(y)) = x*(1 - 1/(e^{2y}+1)),
// y = 0.79788456(x + 0.044715x^3). |err| ~1e-3 << bf16 rounding for |x|<~4.
__device__ __forceinline__ float gelu_f(float x) {
  const float u2 = 1.5957691216057308f * x * (1.0f + 0.044715f * x * x);
  const float e = __expf(u2);
  float r;
  asm("v_rcp_f32 %0, %1" : "=v"(r) : "v"(e + 1.0f));
  return x * (1.0f - r);
}

__device__ __forceinline__ void blockReduce2(float& s, float& s2, float* red) {
  #pragma unroll
  for (int m = 1; m < 64; m <<= 1) {
    s  += __shfl_xor(s,  m);
    s2 += __shfl_xor(s2, m);
  }
  const int wave = threadIdx.x >> 6, lane = threadIdx.x & 63;
  __syncthreads();
  if (lane == 0) { red[wave*2] = s; red[wave*2+1] = s2; }
  __syncthreads();
  s  = red[0] + red[2] + red[4] + red[6];
  s2 = red[1] + red[3] + red[5] + red[7];
}

#define SBAR() do { __builtin_amdgcn_sched_barrier(0); __builtin_amdgcn_s_barrier(); \
                    __builtin_amdgcn_sched_barrier(0); } while (0)
#define LGKM0() do { asm volatile("s_waitcnt lgkmcnt(0)" ::: "memory"); \
                     __builtin_amdgcn_sched_barrier(0); } while (0)
#define LGKMC(n) do { asm volatile("s_waitcnt lgkmcnt(" #n ")" ::: "memory"); \
                      __builtin_amdgcn_sched_barrier(0); } while (0)
#define VMC(n)  do { asm volatile("s_waitcnt vmcnt(" #n ")" ::: "memory"); \
                     __builtin_amdgcn_sched_barrier(0); } while (0)

// ---------------- weight transpose: fp32 [z][R][C] -> bf16 [z][C][R] ----------------

__global__ __launch_bounds__(256)
void transpose_k(const float* __restrict__ in, bf16* __restrict__ out, int R, int C) {
  __shared__ float tile[32][33];
  const int z = blockIdx.z;
  in  += (size_t)z * R * C;
  out += (size_t)z * R * C;
  const int r0 = blockIdx.x * 32, c0 = blockIdx.y * 32;
  const int tx = threadIdx.x, ty = threadIdx.y;   // block (32,8)
  #pragma unroll
  for (int k = 0; k < 4; ++k)
    tile[ty + k*8][tx] = in[(size_t)(r0 + ty + k*8) * C + c0 + tx];
  __syncthreads();
  #pragma unroll
  for (int k = 0; k < 4; ++k)
    out[(size_t)(c0 + ty + k*8) * R + r0 + tx] = (bf16)tile[tx][ty + k*8];
}

// merged QKV weight transpose: z = 0..47, plane z>>4 picks Wq/Wk/Wv

__global__ __launch_bounds__(256)
void transpose_qkv_k(const float* __restrict__ Wq, const float* __restrict__ Wk,
                     const float* __restrict__ Wv, bf16* __restrict__ out) {
  __shared__ float tile[32][33];
  const int z = blockIdx.z;
  const int which = z >> 4, zh = z & 15;
  const float* in = (which == 0 ? Wq : (which == 1 ? Wk : Wv)) + (size_t)zh * 1024 * 64;
  bf16* op = out + (size_t)z * 64 * 1024;
  const int r0 = blockIdx.x * 32, c0 = blockIdx.y * 32;
  const int tx = threadIdx.x, ty = threadIdx.y;   // block (32,8)
  #pragma unroll
  for (int k = 0; k < 4; ++k)
    tile[ty + k*8][tx] = in[(size_t)(r0 + ty + k*8) * 64 + c0 + tx];
  __syncthreads();
  #pragma unroll
  for (int k = 0; k < 4; ++k)
    op[(size_t)(c0 + ty + k*8) * 1024 + r0 + tx] = (bf16)tile[tx][ty + k*8];
}

// ---------------- V transpose: bf16 [z][S][HD] -> [z][HD][S] ----------------

__global__ __launch_bounds__(256)
void transpose_v_k(const bf16* __restrict__ in, bf16* __restrict__ out) {
  __shared__ bf16 t[64*72];
  const int z = blockIdx.y;
  const int s0 = blockIdx.x * 64;
  const bf16* ip = in + (size_t)z * SSS * HDD + (size_t)s0 * HDD;
  bf16* op = out + (size_t)z * SSS * HDD + s0;
  const int tid = threadIdx.x;
  #pragma unroll
  for (int p = 0; p < 2; ++p) {
    const int r = p*32 + (tid >> 3);
    const int c = (tid & 7) * 8;
    const int cs = c ^ (((r >> 3) & 7) << 3);
    *(bf16x8*)&t[r*72 + cs] = *(const bf16x8*)&ip[(size_t)r * HDD + c];
  }
  __syncthreads();
  #pragma unroll
  for (int p = 0; p < 2; ++p) {
    const int hd = p*32 + (tid >> 3);
    const int c0 = (tid & 7) * 8;
    bf16x8 v;
    #pragma unroll
    for (int j = 0; j < 8; ++j) {
      const int r = c0 + j;
      v[j] = t[r*72 + (hd ^ (((r >> 3) & 7) << 3))];
    }
    *(bf16x8*)&op[(size_t)hd * SSS + c0] = v;
  }
}

// ---------------- LN1: x -> bf16 h ----------------

__global__ __launch_bounds__(256)
void ln1_k(const float* __restrict__ x, const float* __restrict__ g,
           const float* __restrict__ b, bf16* __restrict__ out) {
  __shared__ float red[8];
  const int row = blockIdx.x, t = threadIdx.x;
  const float4 v = ((const float4*)(x + (size_t)row * DIMD))[t];
  float s  = v.x + v.y + v.z + v.w;
  float s2 = v.x*v.x + v.y*v.y + v.z*v.z + v.w*v.w;
  blockReduce2(s, s2, red);
  const float mu   = s * (1.0f / DIMD);
  const float var  = s2 * (1.0f / DIMD) - mu * mu;
  const float rstd = rsqrtf(var + 1e-5f);
  const float4 gv = ((const float4*)g)[t];
  const float4 bv = ((const float4*)b)[t];
  bf16x4 o;
  o[0] = (bf16)((v.x - mu) * rstd * gv.x + bv.x);
  o[1] = (bf16)((v.y - mu) * rstd * gv.y + bv.y);
  o[2] = (bf16)((v.z - mu) * rstd * gv.z + bv.z);
  o[3] = (bf16)((v.w - mu) * rstd * gv.w + bv.w);
  *(bf16x4*)(out + (size_t)row * DIMD + t*4) = o;
}

// ---------------- LN2 then FCLN fused ----------------

__global__ __launch_bounds__(256)
void ln2fc_k(const float* __restrict__ x1,
             const float* __restrict__ g2, const float* __restrict__ b2,
             const float* __restrict__ g3, const float* __restrict__ b3,
             bf16* __restrict__ out) {
  __shared__ float red[8];
  const int row = blockIdx.x, t = threadIdx.x;
  const float4 v = ((const float4*)(x1 + (size_t)row * DIMD))[t];
  float s  = v.x + v.y + v.z + v.w;
  float s2 = v.x*v.x + v.y*v.y + v.z*v.z + v.w*v.w;
  blockReduce2(s, s2, red);
  float mu   = s * (1.0f / DIMD);
  float rstd = rsqrtf(s2 * (1.0f / DIMD) - mu * mu + 1e-5f);
  const float4 gv2 = ((const float4*)g2)[t];
  const float4 bv2 = ((const float4*)b2)[t];
  float y0 = (v.x - mu) * rstd * gv2.x + bv2.x;
  float y1 = (v.y - mu) * rstd * gv2.y + bv2.y;
  float y2 = (v.z - mu) * rstd * gv2.z + bv2.z;
  float y3 = (v.w - mu) * rstd * gv2.w + bv2.w;
  s  = y0 + y1 + y2 + y3;
  s2 = y0*y0 + y1*y1 + y2*y2 + y3*y3;
  blockReduce2(s, s2, red);
  mu   = s * (1.0f / DIMD);
  rstd = rsqrtf(s2 * (1.0f / DIMD) - mu * mu + 1e-5f);
  const float4 gv3 = ((const float4*)g3)[t];
  const float4 bv3 = ((const float4*)b3)[t];
  bf16x4 o;
  o[0] = (bf16)((y0 - mu) * rstd * gv3.x + bv3.x);
  o[1] = (bf16)((y1 - mu) * rstd * gv3.y + bv3.y);
  o[2] = (bf16)((y2 - mu) * rstd * gv3.z + bv3.z);
  o[3] = (bf16)((y3 - mu) * rstd * gv3.w + bv3.w);
  *(bf16x4*)(out + (size_t)row * DIMD + t*4) = o;
}

// ================ streamed-read GEMM, BM=64*MH2 x BN=256, BK=64, 512 thr ============
// MH2=2: triple-buffered A + double-buffered B, ONE barrier per K-tile.
// MH2=4: round-11 schedule (2 barriers/tile), proven.

template<int MH2>
__device__ __forceinline__ void load_aH(bf16x8 (&d)[MH2][2], const bf16* base, int roff,
                                        int qv, int sw) {
  #pragma unroll
  for (int mi = 0; mi < MH2; ++mi)
    #pragma unroll
    for (int kk = 0; kk < 2; ++kk)
      d[mi][kk] = *(const bf16x8*)&base[roff + mi*1024 + (((kk<<2)+qv)^sw)*8];
}

__device__ __forceinline__ void load_b2(bf16x8 (&d)[2][2], const bf16* base, int roff,
                                        int qv, int sw) {
  #pragma unroll
  for (int nj = 0; nj < 2; ++nj)
    #pragma unroll
    for (int kk = 0; kk < 2; ++kk)
      d[nj][kk] = *(const bf16x8*)&base[roff + nj*1024 + (((kk<<2)+qv)^sw)*8];
}

template<int AM, int AN, int MH2>
__device__ __forceinline__ void quad(f32x4 (&acc)[2*MH2][4], const bf16x8 (&af)[MH2][2],
                                     const bf16x8 (&bf_)[2][2]) {
  __builtin_amdgcn_s_setprio(1);
  #pragma unroll
  for (int mi = 0; mi < MH2; ++mi)
    #pragma unroll
    for (int nj = 0; nj < 2; ++nj)
      #pragma unroll
      for (int kk = 0; kk < 2; ++kk)
        acc[AM+mi][AN+nj] = mfma_bf16(af[mi][kk], bf_[nj][kk], acc[AM+mi][AN+nj]);
  __builtin_amdgcn_s_setprio(0);
}

template<int EPI, int MH2>
__global__ __launch_bounds__(512)
void gemm8p(const bf16* __restrict__ A, const bf16* __restrict__ Bt,
            int K, int N, int nbx,
            const float* __restrict__ bias, bf16* __restrict__ outB,
            float* __restrict__ outF,
            const float* __restrict__ bq, const float* __restrict__ bk,
            const float* __restrict__ bv) {
  constexpr int BM = 64 * MH2;            // 256 or 128
  constexpr int NAB = (MH2 == 2) ? 3 : 2; // A buffers
  __shared__ bf16 sA[NAB][BM*64];
  __shared__ bf16 sB[2][256*64];
  const int tid = threadIdx.x, wave = tid >> 6, lane = tid & 63;
  const int wm = wave >> 2, wn = wave & 3;

  const int q8 = gridDim.x >> 3;
  const int wg = (blockIdx.x & 7) * q8 + (blockIdx.x >> 3);
  const int by = wg / nbx, bx = wg - by * nbx;
  const int row0 = by * BM, col0 = bx * 256;

  const int l8 = lane >> 3, l7 = lane & 7;
  const int gsw = (l7 ^ l8) * 8;
  const int lo = lane & 15, qv = lane >> 4, sw = lane & 7;

  const bf16* Ags = A  + (size_t)(row0 + wave*8 + l8) * K + gsw;
  const bf16* Bgs = Bt + (size_t)(col0 + wave*8 + l8) * K + gsw;

  #define STAGE_A(buf, r, kt) gld16(Ags + (size_t)(r)*64*K + (kt), &sA[buf][(r)*4096 + wave*512])
  #define STAGE_B(buf, r, kt) gld16(Bgs + (size_t)(r)*64*K + (kt), &sB[buf][(r)*4096 + wave*512])

  const int fA = (wm*(32*MH2) + lo) * 64;     // per-wave M base
  const int fB = (wn*64       + lo) * 64;

  f32x4 acc[2*MH2][4] = {};
  bf16x8 aL[MH2][2], aU[MH2][2], b0[2][2], b1[2][2];
  const int NT = K >> 6;

  if constexpr (MH2 == 2) {
    // ---- triple-A single-barrier schedule
    STAGE_A(0,0,0); STAGE_A(0,1,0);
    STAGE_B(0,0,0); STAGE_B(0,1,0); STAGE_B(0,2,0); STAGE_B(0,3,0);
    STAGE_A(1,0,64); STAGE_A(1,1,64);
    VMC(2); SBAR();

    int ab = 0;
    for (int t = 0; t < NT; ++t) {
      const int bb = t & 1, bn = bb ^ 1;
      const int an = (ab + 2 >= 3) ? (ab - 1) : (ab + 2);
      const int kt1 = (t + 1) << 6, kt2 = (t + 2) << 6;
      const bf16* cA = &sA[ab][0];
      const bf16* cB = &sB[bb][0];

      load_aH<2>(aL, cA, fA, qv, sw);
      load_b2(b0, cB, fB, qv, sw);
      load_b2(b1, cB, fB + 2048, qv, sw);
      load_aH<2>(aU, cA, fA + 2048, qv, sw);
      if (t + 1 < NT) { STAGE_B(bn,0,kt1); STAGE_B(bn,1,kt1);
                        STAGE_B(bn,2,kt1); STAGE_B(bn,3,kt1); }
      if (t + 2 < NT) { STAGE_A(an,0,kt2); STAGE_A(an,1,kt2); }

      LGKMC(8);                       // aL + b0 resident
      quad<0,0,2>(acc, aL, b0);
      LGKMC(4);                       // + b1
      quad<0,2,2>(acc, aL, b1);
      LGKM0();                        // + aU
      quad<2,0,2>(acc, aU, b0);
      quad<2,2,2>(acc, aU, b1);

      if (t + 2 < NT)      { VMC(2); SBAR(); }   // A(t+1)+B(t+1) done; A(t+2) in flight
      else if (t + 1 < NT) { VMC(0); SBAR(); }
      ab = (ab + 1 >= 3) ? 0 : ab + 1;
    }
  } else {
    // ---- round-11 schedule (2 barriers/tile)
    #pragma unroll
    for (int r = 0; r < MH2; ++r) STAGE_A(0, r, 0);
    #pragma unroll
    for (int r = 0; r < 4; ++r)   STAGE_B(0, r, 0);
    #pragma unroll
    for (int j = 0; j < MH2/2; ++j) STAGE_A(1, 2*j, 64);
    VMC(2); SBAR();

    for (int t = 0; t < NT; ++t) {
      const int cur = t & 1, nxt = cur ^ 1;
      const int kt1 = (t + 1) << 6, kt2 = (t + 2) << 6;
      const bf16* cA = &sA[cur][0];
      const bf16* cB = &sB[cur][0];

      load_aH<MH2>(aL, cA, fA, qv, sw);
      load_b2(b0, cB, fB, qv, sw);
      load_b2(b1, cB, fB + 2048, qv, sw);
      load_aH<MH2>(aU, cA, fA + MH2*1024, qv, sw);
      if (t + 1 < NT) {
        #pragma unroll
        for (int j = 0; j < MH2/2; ++j) STAGE_A(nxt, 2*j + 1, kt1);
        #pragma unroll
        for (int r = 0; r < 4; ++r)     STAGE_B(nxt, r, kt1);
      }

      LGKMC(12);
      quad<0,0,MH2>(acc, aL, b0);
      LGKMC(8);
      quad<0,2,MH2>(acc, aL, b1);
      LGKM0();
      SBAR();
      if (t + 2 < NT) {
        #pragma unroll
        for (int j = 0; j < MH2/2; ++j) STAGE_A(cur, 2*j, kt2);
      }
      quad<MH2,0,MH2>(acc, aU, b0);
      quad<MH2,2,MH2>(acc, aU, b1);

      if (t + 1 < NT) {
        if (t + 2 < NT) { VMC(2); } else { VMC(0); }
        SBAR();
      }
    }
  }
  #undef STAGE_A
  #undef STAGE_B

  // ---- epilogue
  #pragma unroll
  for (int mi = 0; mi < 2*MH2; ++mi)
    #pragma unroll
    for (int ni = 0; ni < 4; ++ni)
      #pragma unroll
      for (int i = 0; i < 4; ++i) {
        const int row = row0 + wm*(32*MH2) + mi*16 + qv*4 + i;
        const int col = col0 + wn*64 + ni*16 + lo;
        float v = acc[mi][ni][i];
        if (EPI == 0) {
          const int which = col >> 10, h = (col >> 6) & 15, hd = col & 63;
          const float* bp = (which == 0) ? bq : ((which == 1) ? bk : bv);
          v += bp[h*64 + hd];
          if (which == 0) v *= 0.125f;
          const int b_ = row >> 11, s_ = row & 2047;
          const size_t dst = ((((size_t)which*BBB + b_)*NHD + h)*SSS + s_)*HDD + hd;
          outB[dst] = (bf16)v;
        } else if (EPI == 1) {
          v = gelu_f(v + bias[col]);
          outB[(size_t)row * N + col] = (bf16)v;
        } else {
          v = gelu_f(v + bias[col]);
          outF[(size_t)row * N + col] += v;
        }
      }
}

// ---------------- flash attention (causal) + residual: d_out = x + attn ----------------
// Grid (16, 64): ONE q-tile per block, interleaved bx->qt map {0,15,1,14,...} so any
// contiguous dispatch window is causally balanced; 50.5 KB LDS -> 3 blocks/CU, so
// 1024 blocks = 768 resident + 256 backfill (fixes round-3's no-backfill failure).
// No-max softmax + ones-rows row-sum via PV MFMA; swapped QK^T -> packed b64 P-writes.
// sP halved to [128][40] via ks-split PV (write half, lgkm0, MFMA, write other half;
// rows are wave-private and the DS pipe is in-order per wave).

__global__ __launch_bounds__(256)
void attn_k(const bf16* __restrict__ qkv, const bf16* __restrict__ Vt,
            const float* __restrict__ x, float* __restrict__ out) {
  __shared__ bf16 sK[2][64*72];
  __shared__ bf16 sVt[2][80*72];  // rows 0..63: V^T tile; rows 64..79: constant 1.0
  __shared__ bf16 sP[128*40];     // [q' 0..127][kv-half 0..31 (+8 pad)], wave-private rows
  const int bh = blockIdx.y;
  const int b = bh >> 4, h = bh & 15;
  const int bx = blockIdx.x;
  const int qt = (bx & 1) ? (15 - (bx >> 1)) : (bx >> 1);
  const int q0 = qt * 128;
  const int tid = threadIdx.x, wave = tid >> 6, lane = tid & 63;
  const size_t plane = (size_t)BBB * NHD * SSS * HDD;
  const bf16* Qp  = qkv + ((size_t)b * NHD + h) * SSS * HDD;
  const bf16* Kp  = Qp + plane;
  const bf16* Vtp = Vt + ((size_t)b * NHD + h) * SSS * HDD;  // [HD][S]

  const int r8 = tid >> 3;          // 0..31
  const int c8 = (tid & 7) * 8;     // 0..56
  const int lo = lane & 15, qv = lane >> 4;

  for (int j = tid; j < 16*72; j += 256) {
    sVt[0][64*72 + j] = (bf16)1.0f;
    sVt[1][64*72 + j] = (bf16)1.0f;
  }

  bf16x8 aq[2][2];
  #pragma unroll
  for (int mi = 0; mi < 2; ++mi)
    #pragma unroll
    for (int kk = 0; kk < 2; ++kk)
      aq[mi][kk] = *(const bf16x8*)&Qp[(size_t)(q0 + wave*32 + mi*16 + lo) * HDD
                                       + kk*32 + qv * 8];

  f32x4 o[2][5] = {};   // hf 0..3: O accum; hf 4: row-sum (denominator)

  bf16x8 rk0, rk1, rv0, rv1;
  rk0 = *(const bf16x8*)&Kp[(size_t)r8 * HDD + c8];
  rk1 = *(const bf16x8*)&Kp[(size_t)(32 + r8) * HDD + c8];
  rv0 = *(const bf16x8*)&Vtp[(size_t)r8 * SSS + c8];
  rv1 = *(const bf16x8*)&Vtp[(size_t)(32 + r8) * SSS + c8];

  const int nt = (q0 + 128) / 64;
  for (int t = 0; t < nt; ++t) {
    const int kv0 = t * 64;
    const int buf = t & 1;
    *(bf16x8*)&sK[buf][r8*72 + c8]         = rk0;
    *(bf16x8*)&sK[buf][(32 + r8)*72 + c8]  = rk1;
    *(bf16x8*)&sVt[buf][r8*72 + c8]        = rv0;
    *(bf16x8*)&sVt[buf][(32 + r8)*72 + c8] = rv1;
    __syncthreads();                      // single barrier per tile
    if (t + 1 < nt) {                     // prefetch next tile into regs
      const int kn = kv0 + 64;
      rk0 = *(const bf16x8*)&Kp[(size_t)(kn + r8) * HDD + c8];
      rk1 = *(const bf16x8*)&Kp[(size_t)(kn + 32 + r8) * HDD + c8];
      rv0 = *(const bf16x8*)&Vtp[(size_t)r8 * SSS + kn + c8];
      rv1 = *(const bf16x8*)&Vtp[(size_t)(32 + r8) * SSS + kn + c8];
    }
    if (kv0 <= q0 + wave*32 + 31) {
      // s[mi][ni] = T[kv][q] fragment: rows kv (ni frag, qv*4+i), cols q (mi frag, lo)
      f32x4 s[2][4] = {};
      #pragma unroll
      for (int kk = 0; kk < 2; ++kk)
        #pragma unroll
        for (int ni = 0; ni < 4; ++ni) {
          const bf16x8 ak_ = *(const bf16x8*)&sK[buf][(ni*16 + lo)*72 + kk*32 + qv*8];
          s[0][ni] = mfma_bf16(ak_, aq[0][kk], s[0][ni]);   // A=K, B=Q -> (QK^T)^T
          s[1][ni] = mfma_bf16(ak_, aq[1][kk], s[1][ni]);
        }
      if (kv0 + 63 > q0 + wave*32) {      // causal mask on diagonal tiles
        #pragma unroll
        for (int mi = 0; mi < 2; ++mi)
          #pragma unroll
          for (int ni = 0; ni < 4; ++ni)
            #pragma unroll
            for (int i = 0; i < 4; ++i) {
              const int kvg = kv0 + ni*16 + qv*4 + i;
              const int qg  = q0 + wave*32 + mi*16 + lo;
              if (kvg > qg) s[mi][ni][i] = -1e30f;
            }
      }
      // ks-split PV: for each kv-half, write exp'd P (packed b64) then MFMA
      #pragma unroll
      for (int ks = 0; ks < 2; ++ks) {
        #pragma unroll
        for (int mi = 0; mi < 2; ++mi)
          #pragma unroll
          for (int nh = 0; nh < 2; ++nh) {
            const int ni = ks*2 + nh;
            bf16x4 pk;
            #pragma unroll
            for (int i = 0; i < 4; ++i) pk[i] = (bf16)__expf(s[mi][ni][i]);
            *(bf16x4*)&sP[(wave*32 + mi*16 + lo)*40 + nh*16 + qv*4] = pk;
          }
        asm volatile("s_waitcnt lgkmcnt(0)" ::: "memory");  // sP rows are wave-private
        __builtin_amdgcn_sched_barrier(0);
        bf16x8 ap[2];
        ap[0] = *(const bf16x8*)&sP[(wave*32 +      lo)*40 + qv*8];
        ap[1] = *(const bf16x8*)&sP[(wave*32 + 16 + lo)*40 + qv*8];
        #pragma unroll
        for (int hf = 0; hf < 5; ++hf) {   // hf=4: ones-rows -> row-sum
          const bf16x8 bv_ = *(const bf16x8*)&sVt[buf][(hf*16 + lo)*72 + ks*32 + qv*8];
          o[0][hf] = mfma_bf16(ap[0], bv_, o[0][hf]);
          o[1][hf] = mfma_bf16(ap[1], bv_, o[1][hf]);
        }
        __builtin_amdgcn_sched_barrier(0);  // keep half-1 writes after half-0 reads
      }
    }
  }
  #pragma unroll
  for (int mi = 0; mi < 2; ++mi) {
    float inv[4];
    #pragma unroll
    for (int i = 0; i < 4; ++i) inv[i] = 1.0f / o[mi][4][i];
    #pragma unroll
    for (int hf = 0; hf < 4; ++hf)
      #pragma unroll
      for (int i = 0; i < 4; ++i) {
        const int srow = q0 + wave*32 + mi*16 + qv*4 + i;
        const int col  = h*HDD + hf*16 + lo;
        const size_t idx = ((size_t)b * SSS + srow) * DIMD + col;
        out[idx] = x[idx] + o[mi][hf][i] * inv[i];
      }
  }
}

// ---------------- launch ----------------

extern "C" void kernel_launch(void* const* d_in, const int* in_sizes, int n_in,
                              void* d_out, int out_size, void* d_ws, size_t ws_size,
                              hipStream_t stream) {
  const float* x     = (const float*)d_in[0];
  const float* ln1g  = (const float*)d_in[1];
  const float* ln1b  = (const float*)d_in[2];
  const float* Wq    = (const float*)d_in[3];
  const float* bq    = (const float*)d_in[4];
  const float* Wk    = (const float*)d_in[5];
  const float* bk    = (const float*)d_in[6];
  const float* Wv    = (const float*)d_in[7];
  const float* bv    = (const float*)d_in[8];
  const float* ln2g  = (const float*)d_in[9];
  const float* ln2b  = (const float*)d_in[10];
  const float* fclng = (const float*)d_in[11];
  const float* fclnb = (const float*)d_in[12];
  const float* W1    = (const float*)d_in[13];
  const float* b1    = (const float*)d_in[14];
  const float* W2    = (const float*)d_in[15];
  const float* b2    = (const float*)d_in[16];
  float* out = (float*)d_out;

  // ws layout (bytes), total 106,954,752
  char* ws = (char*)d_ws;
  bf16* h     = (bf16*)(ws);                 // 16 MB  [8192][1024]; reused as Vt then h2
  bf16* Wqkvt = (bf16*)(ws + 16777216);      // 6 MB   [3072][1024] K-major
  bf16* W1t   = (bf16*)(ws + 23068672);      // 8 MB   [4096][1024]
  bf16* W2t   = (bf16*)(ws + 31457280);      // 8 MB   [1024][4096]
  bf16* qkv   = (bf16*)(ws + 39845888);      // 48 MB  [3][B][NH][S][HD]
  bf16* u     = (bf16*)(ws + 39845888);      // 64 MB  [8192][4096]  (aliases qkv, disjoint in time)
  bf16* VtB   = h;                           // 16 MB  [B][NH][HD][S]
  const size_t plane = (size_t)BBB * NHD * SSS * HDD;

  const dim3 tb(32, 8);
  transpose_qkv_k<<<dim3(32, 2, 48), tb, 0, stream>>>(Wq, Wk, Wv, Wqkvt);
  transpose_k<<<dim3(32, 128, 1), tb, 0, stream>>>(W1, W1t, 1024, 4096);
  transpose_k<<<dim3(128, 32, 1), tb, 0, stream>>>(W2, W2t, 4096, 1024);

  ln1_k<<<MMM, 256, 0, stream>>>(x, ln1g, ln1b, h);

  // QKV: M=8192, N=3072, K=1024 -> BM=128: 64x12 = 768 blocks
  gemm8p<0,2><<<dim3(768), 512, 0, stream>>>(h, Wqkvt, 1024, 3072, 12,
                                             nullptr, qkv, nullptr, bq, bk, bv);

  transpose_v_k<<<dim3(SSS/64, BBB*NHD), 256, 0, stream>>>(qkv + 2*plane, VtB);

  // attn: 1024 blocks (one q-tile each), 3 blocks/CU capacity -> 256-block backfill
  attn_k<<<dim3(16, BBB*NHD), 256, 0, stream>>>(qkv, VtB, x, out);

  ln2fc_k<<<MMM, 256, 0, stream>>>(out, ln2g, ln2b, fclng, fclnb, h);

  // MLP1: M=8192, N=4096, K=1024 -> 32x16 = 512 blocks (r11 schedule, MH2=4)
  gemm8p<1,4><<<dim3(512), 512, 0, stream>>>(h, W1t, 1024, 4096, 16,
                                             b1, u, nullptr, nullptr, nullptr, nullptr);

  // MLP2: M=8192, N=1024, K=4096 -> BM=128: 64x4 = 256 blocks (triple-A, MH2=2)
  gemm8p<2,2><<<dim3(256), 512, 0, stream>>>(u, W2t, 4096, 1024, 4,
                                             b2, nullptr, out, nullptr, nullptr, nullptr);
}

// Round 16
// 335.545 us; speedup vs baseline: 1.1344x; 1.1344x over previous
//
#include <hip/hip_runtime.h>
#include <math.h>

// Problem constants
#define DIMD 1024
#define NHD  16
#define HDD  64
#define BBB  4
#define SSS  2048
#define MMM  (BBB*SSS)   // 8192 rows

typedef __bf16 bf16;
typedef __bf16 bf16x8 __attribute__((ext_vector_type(8)));
typedef __bf16 bf16x4 __attribute__((ext_vector_type(4)));
typedef float  f32x4  __attribute__((ext_vector_type(4)));

// ---------------- helpers ----------------

__device__ __forceinline__ void gld16(const void* g, void* l) {
  __builtin_amdgcn_global_load_lds((const __attribute__((address_space(1))) void*)g,
                                   (__attribute__((address_space(3))) void*)l,
                                   16, 0, 0);
}

__device__ __forceinline__ f32x4 mfma_bf16(bf16x8 a, bf16x8 b, f32x4 c) {
  return __builtin_amdgcn_mfma_f32_16x16x32_bf16(a, b, c, 0, 0, 0);
}

// tanh-form GELU via sigmoid identity: 0.5x(1+tanh(y)) = x*(1 - 1/(e^{2y}+1)),
// y = 0.79788456(x + 0.044715x^3). |err| ~1e-3 << bf16 rounding for |x|<~4.
__device__ __forceinline__ float gelu_f(float x) {
  const float u2 = 1.5957691216057308f * x * (1.0f + 0.044715f * x * x);
  const float e = __expf(u2);
  float r;
  asm("v_rcp_f32 %0, %1" : "=v"(r) : "v"(e + 1.0f));
  return x * (1.0f - r);
}

__device__ __forceinline__ void blockReduce2(float& s, float& s2, float* red) {
  #pragma unroll
  for (int m = 1; m < 64; m <<= 1) {
    s  += __shfl_xor(s,  m);
    s2 += __shfl_xor(s2, m);
  }
  const int wave = threadIdx.x >> 6, lane = threadIdx.x & 63;
  __syncthreads();
  if (lane == 0) { red[wave*2] = s; red[wave*2+1] = s2; }
  __syncthreads();
  s  = red[0] + red[2] + red[4] + red[6];
  s2 = red[1] + red[3] + red[5] + red[7];
}

#define SBAR() do { __builtin_amdgcn_sched_barrier(0); __builtin_amdgcn_s_barrier(); \
                    __builtin_amdgcn_sched_barrier(0); } while (0)
#define LGKM0() do { asm volatile("s_waitcnt lgkmcnt(0)" ::: "memory"); \
                     __builtin_amdgcn_sched_barrier(0); } while (0)
#define LGKMC(n) do { asm volatile("s_waitcnt lgkmcnt(" #n ")" ::: "memory"); \
                      __builtin_amdgcn_sched_barrier(0); } while (0)
#define VMC(n)  do { asm volatile("s_waitcnt vmcnt(" #n ")" ::: "memory"); \
                     __builtin_amdgcn_sched_barrier(0); } while (0)

// ---------------- weight transpose: fp32 [z][R][C] -> bf16 [z][C][R] ----------------

__global__ __launch_bounds__(256)
void transpose_k(const float* __restrict__ in, bf16* __restrict__ out, int R, int C) {
  __shared__ float tile[32][33];
  const int z = blockIdx.z;
  in  += (size_t)z * R * C;
  out += (size_t)z * R * C;
  const int r0 = blockIdx.x * 32, c0 = blockIdx.y * 32;
  const int tx = threadIdx.x, ty = threadIdx.y;   // block (32,8)
  #pragma unroll
  for (int k = 0; k < 4; ++k)
    tile[ty + k*8][tx] = in[(size_t)(r0 + ty + k*8) * C + c0 + tx];
  __syncthreads();
  #pragma unroll
  for (int k = 0; k < 4; ++k)
    out[(size_t)(c0 + ty + k*8) * R + r0 + tx] = (bf16)tile[tx][ty + k*8];
}

// merged QKV weight transpose: z = 0..47, plane z>>4 picks Wq/Wk/Wv

__global__ __launch_bounds__(256)
void transpose_qkv_k(const float* __restrict__ Wq, const float* __restrict__ Wk,
                     const float* __restrict__ Wv, bf16* __restrict__ out) {
  __shared__ float tile[32][33];
  const int z = blockIdx.z;
  const int which = z >> 4, zh = z & 15;
  const float* in = (which == 0 ? Wq : (which == 1 ? Wk : Wv)) + (size_t)zh * 1024 * 64;
  bf16* op = out + (size_t)z * 64 * 1024;
  const int r0 = blockIdx.x * 32, c0 = blockIdx.y * 32;
  const int tx = threadIdx.x, ty = threadIdx.y;   // block (32,8)
  #pragma unroll
  for (int k = 0; k < 4; ++k)
    tile[ty + k*8][tx] = in[(size_t)(r0 + ty + k*8) * 64 + c0 + tx];
  __syncthreads();
  #pragma unroll
  for (int k = 0; k < 4; ++k)
    op[(size_t)(c0 + ty + k*8) * 1024 + r0 + tx] = (bf16)tile[tx][ty + k*8];
}

// ---------------- V transpose: bf16 [z][S][HD] -> [z][HD][S] ----------------

__global__ __launch_bounds__(256)
void transpose_v_k(const bf16* __restrict__ in, bf16* __restrict__ out) {
  __shared__ bf16 t[64*72];
  const int z = blockIdx.y;
  const int s0 = blockIdx.x * 64;
  const bf16* ip = in + (size_t)z * SSS * HDD + (size_t)s0 * HDD;
  bf16* op = out + (size_t)z * SSS * HDD + s0;
  const int tid = threadIdx.x;
  #pragma unroll
  for (int p = 0; p < 2; ++p) {
    const int r = p*32 + (tid >> 3);
    const int c = (tid & 7) * 8;
    const int cs = c ^ (((r >> 3) & 7) << 3);
    *(bf16x8*)&t[r*72 + cs] = *(const bf16x8*)&ip[(size_t)r * HDD + c];
  }
  __syncthreads();
  #pragma unroll
  for (int p = 0; p < 2; ++p) {
    const int hd = p*32 + (tid >> 3);
    const int c0 = (tid & 7) * 8;
    bf16x8 v;
    #pragma unroll
    for (int j = 0; j < 8; ++j) {
      const int r = c0 + j;
      v[j] = t[r*72 + (hd ^ (((r >> 3) & 7) << 3))];
    }
    *(bf16x8*)&op[(size_t)hd * SSS + c0] = v;
  }
}

// ---------------- LN1: x -> bf16 h ----------------

__global__ __launch_bounds__(256)
void ln1_k(const float* __restrict__ x, const float* __restrict__ g,
           const float* __restrict__ b, bf16* __restrict__ out) {
  __shared__ float red[8];
  const int row = blockIdx.x, t = threadIdx.x;
  const float4 v = ((const float4*)(x + (size_t)row * DIMD))[t];
  float s  = v.x + v.y + v.z + v.w;
  float s2 = v.x*v.x + v.y*v.y + v.z*v.z + v.w*v.w;
  blockReduce2(s, s2, red);
  const float mu   = s * (1.0f / DIMD);
  const float var  = s2 * (1.0f / DIMD) - mu * mu;
  const float rstd = rsqrtf(var + 1e-5f);
  const float4 gv = ((const float4*)g)[t];
  const float4 bv = ((const float4*)b)[t];
  bf16x4 o;
  o[0] = (bf16)((v.x - mu) * rstd * gv.x + bv.x);
  o[1] = (bf16)((v.y - mu) * rstd * gv.y + bv.y);
  o[2] = (bf16)((v.z - mu) * rstd * gv.z + bv.z);
  o[3] = (bf16)((v.w - mu) * rstd * gv.w + bv.w);
  *(bf16x4*)(out + (size_t)row * DIMD + t*4) = o;
}

// ---------------- LN2 then FCLN fused ----------------

__global__ __launch_bounds__(256)
void ln2fc_k(const float* __restrict__ x1,
             const float* __restrict__ g2, const float* __restrict__ b2,
             const float* __restrict__ g3, const float* __restrict__ b3,
             bf16* __restrict__ out) {
  __shared__ float red[8];
  const int row = blockIdx.x, t = threadIdx.x;
  const float4 v = ((const float4*)(x1 + (size_t)row * DIMD))[t];
  float s  = v.x + v.y + v.z + v.w;
  float s2 = v.x*v.x + v.y*v.y + v.z*v.z + v.w*v.w;
  blockReduce2(s, s2, red);
  float mu   = s * (1.0f / DIMD);
  float rstd = rsqrtf(s2 * (1.0f / DIMD) - mu * mu + 1e-5f);
  const float4 gv2 = ((const float4*)g2)[t];
  const float4 bv2 = ((const float4*)b2)[t];
  float y0 = (v.x - mu) * rstd * gv2.x + bv2.x;
  float y1 = (v.y - mu) * rstd * gv2.y + bv2.y;
  float y2 = (v.z - mu) * rstd * gv2.z + bv2.z;
  float y3 = (v.w - mu) * rstd * gv2.w + bv2.w;
  s  = y0 + y1 + y2 + y3;
  s2 = y0*y0 + y1*y1 + y2*y2 + y3*y3;
  blockReduce2(s, s2, red);
  mu   = s * (1.0f / DIMD);
  rstd = rsqrtf(s2 * (1.0f / DIMD) - mu * mu + 1e-5f);
  const float4 gv3 = ((const float4*)g3)[t];
  const float4 bv3 = ((const float4*)b3)[t];
  bf16x4 o;
  o[0] = (bf16)((y0 - mu) * rstd * gv3.x + bv3.x);
  o[1] = (bf16)((y1 - mu) * rstd * gv3.y + bv3.y);
  o[2] = (bf16)((y2 - mu) * rstd * gv3.z + bv3.z);
  o[3] = (bf16)((y3 - mu) * rstd * gv3.w + bv3.w);
  *(bf16x4*)(out + (size_t)row * DIMD + t*4) = o;
}

// ================ streamed-read GEMM, BM=64*MH2 x BN=256, BK=64, 512 thr ============
// MH2=2: triple-buffered A + double-buffered B, ONE barrier per K-tile.
// MH2=4: round-11 schedule (2 barriers/tile), proven.

template<int MH2>
__device__ __forceinline__ void load_aH(bf16x8 (&d)[MH2][2], const bf16* base, int roff,
                                        int qv, int sw) {
  #pragma unroll
  for (int mi = 0; mi < MH2; ++mi)
    #pragma unroll
    for (int kk = 0; kk < 2; ++kk)
      d[mi][kk] = *(const bf16x8*)&base[roff + mi*1024 + (((kk<<2)+qv)^sw)*8];
}

__device__ __forceinline__ void load_b2(bf16x8 (&d)[2][2], const bf16* base, int roff,
                                        int qv, int sw) {
  #pragma unroll
  for (int nj = 0; nj < 2; ++nj)
    #pragma unroll
    for (int kk = 0; kk < 2; ++kk)
      d[nj][kk] = *(const bf16x8*)&base[roff + nj*1024 + (((kk<<2)+qv)^sw)*8];
}

template<int AM, int AN, int MH2>
__device__ __forceinline__ void quad(f32x4 (&acc)[2*MH2][4], const bf16x8 (&af)[MH2][2],
                                     const bf16x8 (&bf_)[2][2]) {
  __builtin_amdgcn_s_setprio(1);
  #pragma unroll
  for (int mi = 0; mi < MH2; ++mi)
    #pragma unroll
    for (int nj = 0; nj < 2; ++nj)
      #pragma unroll
      for (int kk = 0; kk < 2; ++kk)
        acc[AM+mi][AN+nj] = mfma_bf16(af[mi][kk], bf_[nj][kk], acc[AM+mi][AN+nj]);
  __builtin_amdgcn_s_setprio(0);
}

template<int EPI, int MH2>
__global__ __launch_bounds__(512)
void gemm8p(const bf16* __restrict__ A, const bf16* __restrict__ Bt,
            int K, int N, int nbx,
            const float* __restrict__ bias, bf16* __restrict__ outB,
            float* __restrict__ outF,
            const float* __restrict__ bq, const float* __restrict__ bk,
            const float* __restrict__ bv) {
  constexpr int BM = 64 * MH2;            // 256 or 128
  constexpr int NAB = (MH2 == 2) ? 3 : 2; // A buffers
  __shared__ bf16 sA[NAB][BM*64];
  __shared__ bf16 sB[2][256*64];
  const int tid = threadIdx.x, wave = tid >> 6, lane = tid & 63;
  const int wm = wave >> 2, wn = wave & 3;

  const int q8 = gridDim.x >> 3;
  const int wg = (blockIdx.x & 7) * q8 + (blockIdx.x >> 3);
  const int by = wg / nbx, bx = wg - by * nbx;
  const int row0 = by * BM, col0 = bx * 256;

  const int l8 = lane >> 3, l7 = lane & 7;
  const int gsw = (l7 ^ l8) * 8;
  const int lo = lane & 15, qv = lane >> 4, sw = lane & 7;

  const bf16* Ags = A  + (size_t)(row0 + wave*8 + l8) * K + gsw;
  const bf16* Bgs = Bt + (size_t)(col0 + wave*8 + l8) * K + gsw;

  #define STAGE_A(buf, r, kt) gld16(Ags + (size_t)(r)*64*K + (kt), &sA[buf][(r)*4096 + wave*512])
  #define STAGE_B(buf, r, kt) gld16(Bgs + (size_t)(r)*64*K + (kt), &sB[buf][(r)*4096 + wave*512])

  const int fA = (wm*(32*MH2) + lo) * 64;     // per-wave M base
  const int fB = (wn*64       + lo) * 64;

  f32x4 acc[2*MH2][4] = {};
  bf16x8 aL[MH2][2], aU[MH2][2], b0[2][2], b1[2][2];
  const int NT = K >> 6;

  if constexpr (MH2 == 2) {
    // ---- triple-A single-barrier schedule
    STAGE_A(0,0,0); STAGE_A(0,1,0);
    STAGE_B(0,0,0); STAGE_B(0,1,0); STAGE_B(0,2,0); STAGE_B(0,3,0);
    STAGE_A(1,0,64); STAGE_A(1,1,64);
    VMC(2); SBAR();

    int ab = 0;
    for (int t = 0; t < NT; ++t) {
      const int bb = t & 1, bn = bb ^ 1;
      const int an = (ab + 2 >= 3) ? (ab - 1) : (ab + 2);
      const int kt1 = (t + 1) << 6, kt2 = (t + 2) << 6;
      const bf16* cA = &sA[ab][0];
      const bf16* cB = &sB[bb][0];

      load_aH<2>(aL, cA, fA, qv, sw);
      load_b2(b0, cB, fB, qv, sw);
      load_b2(b1, cB, fB + 2048, qv, sw);
      load_aH<2>(aU, cA, fA + 2048, qv, sw);
      if (t + 1 < NT) { STAGE_B(bn,0,kt1); STAGE_B(bn,1,kt1);
                        STAGE_B(bn,2,kt1); STAGE_B(bn,3,kt1); }
      if (t + 2 < NT) { STAGE_A(an,0,kt2); STAGE_A(an,1,kt2); }

      LGKMC(8);                       // aL + b0 resident
      quad<0,0,2>(acc, aL, b0);
      LGKMC(4);                       // + b1
      quad<0,2,2>(acc, aL, b1);
      LGKM0();                        // + aU
      quad<2,0,2>(acc, aU, b0);
      quad<2,2,2>(acc, aU, b1);

      if (t + 2 < NT)      { VMC(2); SBAR(); }   // A(t+1)+B(t+1) done; A(t+2) in flight
      else if (t + 1 < NT) { VMC(0); SBAR(); }
      ab = (ab + 1 >= 3) ? 0 : ab + 1;
    }
  } else {
    // ---- round-11 schedule (2 barriers/tile)
    #pragma unroll
    for (int r = 0; r < MH2; ++r) STAGE_A(0, r, 0);
    #pragma unroll
    for (int r = 0; r < 4; ++r)   STAGE_B(0, r, 0);
    #pragma unroll
    for (int j = 0; j < MH2/2; ++j) STAGE_A(1, 2*j, 64);
    VMC(2); SBAR();

    for (int t = 0; t < NT; ++t) {
      const int cur = t & 1, nxt = cur ^ 1;
      const int kt1 = (t + 1) << 6, kt2 = (t + 2) << 6;
      const bf16* cA = &sA[cur][0];
      const bf16* cB = &sB[cur][0];

      load_aH<MH2>(aL, cA, fA, qv, sw);
      load_b2(b0, cB, fB, qv, sw);
      load_b2(b1, cB, fB + 2048, qv, sw);
      load_aH<MH2>(aU, cA, fA + MH2*1024, qv, sw);
      if (t + 1 < NT) {
        #pragma unroll
        for (int j = 0; j < MH2/2; ++j) STAGE_A(nxt, 2*j + 1, kt1);
        #pragma unroll
        for (int r = 0; r < 4; ++r)     STAGE_B(nxt, r, kt1);
      }

      LGKMC(12);
      quad<0,0,MH2>(acc, aL, b0);
      LGKMC(8);
      quad<0,2,MH2>(acc, aL, b1);
      LGKM0();
      SBAR();
      if (t + 2 < NT) {
        #pragma unroll
        for (int j = 0; j < MH2/2; ++j) STAGE_A(cur, 2*j, kt2);
      }
      quad<MH2,0,MH2>(acc, aU, b0);
      quad<MH2,2,MH2>(acc, aU, b1);

      if (t + 1 < NT) {
        if (t + 2 < NT) { VMC(2); } else { VMC(0); }
        SBAR();
      }
    }
  }
  #undef STAGE_A
  #undef STAGE_B

  // ---- epilogue
  #pragma unroll
  for (int mi = 0; mi < 2*MH2; ++mi)
    #pragma unroll
    for (int ni = 0; ni < 4; ++ni)
      #pragma unroll
      for (int i = 0; i < 4; ++i) {
        const int row = row0 + wm*(32*MH2) + mi*16 + qv*4 + i;
        const int col = col0 + wn*64 + ni*16 + lo;
        float v = acc[mi][ni][i];
        if (EPI == 0) {
          const int which = col >> 10, h = (col >> 6) & 15, hd = col & 63;
          const float* bp = (which == 0) ? bq : ((which == 1) ? bk : bv);
          v += bp[h*64 + hd];
          if (which == 0) v *= 0.125f;
          const int b_ = row >> 11, s_ = row & 2047;
          const size_t dst = ((((size_t)which*BBB + b_)*NHD + h)*SSS + s_)*HDD + hd;
          outB[dst] = (bf16)v;
        } else if (EPI == 1) {
          v = gelu_f(v + bias[col]);
          outB[(size_t)row * N + col] = (bf16)v;
        } else {
          v = gelu_f(v + bias[col]);
          outF[(size_t)row * N + col] += v;
        }
      }
}

// ---------------- flash attention (causal) + residual: d_out = x + attn ----------------
// Grid (8, 64): block processes q-tiles {bx, 15-bx} (constant 34 KV-tiles = causal balance).
// No-max softmax + ones-rows row-sum via PV MFMA; swapped QK^T -> packed b64 P-writes.
// K/Vt double-buffered: ONE barrier per KV-tile.

__global__ __launch_bounds__(256)
void attn_k(const bf16* __restrict__ qkv, const bf16* __restrict__ Vt,
            const float* __restrict__ x, float* __restrict__ out) {
  __shared__ bf16 sK[2][64*72];
  __shared__ bf16 sVt[2][80*72];  // rows 0..63: V^T tile; rows 64..79: constant 1.0
  __shared__ bf16 sP[128*72];     // [q' 0..127][kv 0..63], wave-private rows
  const int bh = blockIdx.y;
  const int b = bh >> 4, h = bh & 15;
  const int tid = threadIdx.x, wave = tid >> 6, lane = tid & 63;
  const size_t plane = (size_t)BBB * NHD * SSS * HDD;
  const bf16* Qp  = qkv + ((size_t)b * NHD + h) * SSS * HDD;
  const bf16* Kp  = Qp + plane;
  const bf16* Vtp = Vt + ((size_t)b * NHD + h) * SSS * HDD;  // [HD][S]

  const int r8 = tid >> 3;          // 0..31
  const int c8 = (tid & 7) * 8;     // 0..56
  const int lo = lane & 15, qv = lane >> 4;

  for (int j = tid; j < 16*72; j += 256) {
    sVt[0][64*72 + j] = (bf16)1.0f;
    sVt[1][64*72 + j] = (bf16)1.0f;
  }

  for (int pass = 0; pass < 2; ++pass) {
    const int q0 = (pass == 0 ? (int)blockIdx.x : 15 - (int)blockIdx.x) * 128;

    bf16x8 aq[2][2];
    #pragma unroll
    for (int mi = 0; mi < 2; ++mi)
      #pragma unroll
      for (int kk = 0; kk < 2; ++kk)
        aq[mi][kk] = *(const bf16x8*)&Qp[(size_t)(q0 + wave*32 + mi*16 + lo) * HDD
                                         + kk*32 + qv * 8];

    f32x4 o[2][5] = {};   // hf 0..3: O accum; hf 4: row-sum (denominator)

    bf16x8 rk0, rk1, rv0, rv1;
    rk0 = *(const bf16x8*)&Kp[(size_t)r8 * HDD + c8];
    rk1 = *(const bf16x8*)&Kp[(size_t)(32 + r8) * HDD + c8];
    rv0 = *(const bf16x8*)&Vtp[(size_t)r8 * SSS + c8];
    rv1 = *(const bf16x8*)&Vtp[(size_t)(32 + r8) * SSS + c8];

    const int nt = (q0 + 128) / 64;
    for (int t = 0; t < nt; ++t) {
      const int kv0 = t * 64;
      const int buf = t & 1;
      *(bf16x8*)&sK[buf][r8*72 + c8]         = rk0;
      *(bf16x8*)&sK[buf][(32 + r8)*72 + c8]  = rk1;
      *(bf16x8*)&sVt[buf][r8*72 + c8]        = rv0;
      *(bf16x8*)&sVt[buf][(32 + r8)*72 + c8] = rv1;
      __syncthreads();                      // single barrier per tile
      if (t + 1 < nt) {                     // prefetch next tile into regs
        const int kn = kv0 + 64;
        rk0 = *(const bf16x8*)&Kp[(size_t)(kn + r8) * HDD + c8];
        rk1 = *(const bf16x8*)&Kp[(size_t)(kn + 32 + r8) * HDD + c8];
        rv0 = *(const bf16x8*)&Vtp[(size_t)r8 * SSS + kn + c8];
        rv1 = *(const bf16x8*)&Vtp[(size_t)(32 + r8) * SSS + kn + c8];
      }
      if (kv0 <= q0 + wave*32 + 31) {
        // s[mi][ni] = T[kv][q] fragment: rows kv (ni frag, qv*4+i), cols q (mi frag, lo)
        f32x4 s[2][4] = {};
        #pragma unroll
        for (int kk = 0; kk < 2; ++kk)
          #pragma unroll
          for (int ni = 0; ni < 4; ++ni) {
            const bf16x8 ak_ = *(const bf16x8*)&sK[buf][(ni*16 + lo)*72 + kk*32 + qv*8];
            s[0][ni] = mfma_bf16(ak_, aq[0][kk], s[0][ni]);   // A=K, B=Q -> (QK^T)^T
            s[1][ni] = mfma_bf16(ak_, aq[1][kk], s[1][ni]);
          }
        if (kv0 + 63 > q0 + wave*32) {      // causal mask on diagonal tiles
          #pragma unroll
          for (int mi = 0; mi < 2; ++mi)
            #pragma unroll
            for (int ni = 0; ni < 4; ++ni)
              #pragma unroll
              for (int i = 0; i < 4; ++i) {
                const int kvg = kv0 + ni*16 + qv*4 + i;
                const int qg  = q0 + wave*32 + mi*16 + lo;
                if (kvg > qg) s[mi][ni][i] = -1e30f;
              }
        }
        // p = exp(s); pack 4 consecutive kv into one b64 write
        #pragma unroll
        for (int mi = 0; mi < 2; ++mi)
          #pragma unroll
          for (int ni = 0; ni < 4; ++ni) {
            bf16x4 pk;
            #pragma unroll
            for (int i = 0; i < 4; ++i) pk[i] = (bf16)__expf(s[mi][ni][i]);
            *(bf16x4*)&sP[(wave*32 + mi*16 + lo)*72 + ni*16 + qv*4] = pk;
          }
        asm volatile("s_waitcnt lgkmcnt(0)" ::: "memory");  // sP rows are wave-private
        __builtin_amdgcn_sched_barrier(0);
        #pragma unroll
        for (int ks = 0; ks < 2; ++ks) {
          bf16x8 ap[2];
          ap[0] = *(const bf16x8*)&sP[(wave*32 +      lo)*72 + ks*32 + qv*8];
          ap[1] = *(const bf16x8*)&sP[(wave*32 + 16 + lo)*72 + ks*32 + qv*8];
          #pragma unroll
          for (int hf = 0; hf < 5; ++hf) {   // hf=4: ones-rows -> row-sum
            const bf16x8 bv_ = *(const bf16x8*)&sVt[buf][(hf*16 + lo)*72 + ks*32 + qv*8];
            o[0][hf] = mfma_bf16(ap[0], bv_, o[0][hf]);
            o[1][hf] = mfma_bf16(ap[1], bv_, o[1][hf]);
          }
        }
      }
    }
    #pragma unroll
    for (int mi = 0; mi < 2; ++mi) {
      float inv[4];
      #pragma unroll
      for (int i = 0; i < 4; ++i) inv[i] = 1.0f / o[mi][4][i];
      #pragma unroll
      for (int hf = 0; hf < 4; ++hf)
        #pragma unroll
        for (int i = 0; i < 4; ++i) {
          const int srow = q0 + wave*32 + mi*16 + qv*4 + i;
          const int col  = h*HDD + hf*16 + lo;
          const size_t idx = ((size_t)b * SSS + srow) * DIMD + col;
          out[idx] = x[idx] + o[mi][hf][i] * inv[i];
        }
    }
  }
}

// ---------------- launch ----------------

extern "C" void kernel_launch(void* const* d_in, const int* in_sizes, int n_in,
                              void* d_out, int out_size, void* d_ws, size_t ws_size,
                              hipStream_t stream) {
  const float* x     = (const float*)d_in[0];
  const float* ln1g  = (const float*)d_in[1];
  const float* ln1b  = (const float*)d_in[2];
  const float* Wq    = (const float*)d_in[3];
  const float* bq    = (const float*)d_in[4];
  const float* Wk    = (const float*)d_in[5];
  const float* bk    = (const float*)d_in[6];
  const float* Wv    = (const float*)d_in[7];
  const float* bv    = (const float*)d_in[8];
  const float* ln2g  = (const float*)d_in[9];
  const float* ln2b  = (const float*)d_in[10];
  const float* fclng = (const float*)d_in[11];
  const float* fclnb = (const float*)d_in[12];
  const float* W1    = (const float*)d_in[13];
  const float* b1    = (const float*)d_in[14];
  const float* W2    = (const float*)d_in[15];
  const float* b2    = (const float*)d_in[16];
  float* out = (float*)d_out;

  // ws layout (bytes), total 106,954,752
  char* ws = (char*)d_ws;
  bf16* h     = (bf16*)(ws);                 // 16 MB  [8192][1024]; reused as Vt then h2
  bf16* Wqkvt = (bf16*)(ws + 16777216);      // 6 MB   [3072][1024] K-major
  bf16* W1t   = (bf16*)(ws + 23068672);      // 8 MB   [4096][1024]
  bf16* W2t   = (bf16*)(ws + 31457280);      // 8 MB   [1024][4096]
  bf16* qkv   = (bf16*)(ws + 39845888);      // 48 MB  [3][B][NH][S][HD]
  bf16* u     = (bf16*)(ws + 39845888);      // 64 MB  [8192][4096]  (aliases qkv, disjoint in time)
  bf16* VtB   = h;                           // 16 MB  [B][NH][HD][S]
  const size_t plane = (size_t)BBB * NHD * SSS * HDD;

  const dim3 tb(32, 8);
  transpose_qkv_k<<<dim3(32, 2, 48), tb, 0, stream>>>(Wq, Wk, Wv, Wqkvt);
  transpose_k<<<dim3(32, 128, 1), tb, 0, stream>>>(W1, W1t, 1024, 4096);
  transpose_k<<<dim3(128, 32, 1), tb, 0, stream>>>(W2, W2t, 4096, 1024);

  ln1_k<<<MMM, 256, 0, stream>>>(x, ln1g, ln1b, h);

  // QKV: M=8192, N=3072, K=1024 -> BM=128: 64x12 = 768 blocks
  gemm8p<0,2><<<dim3(768), 512, 0, stream>>>(h, Wqkvt, 1024, 3072, 12,
                                             nullptr, qkv, nullptr, bq, bk, bv);

  transpose_v_k<<<dim3(SSS/64, BBB*NHD), 256, 0, stream>>>(qkv + 2*plane, VtB);

  attn_k<<<dim3(8, BBB*NHD), 256, 0, stream>>>(qkv, VtB, x, out);

  ln2fc_k<<<MMM, 256, 0, stream>>>(out, ln2g, ln2b, fclng, fclnb, h);

  // MLP1: M=8192, N=4096, K=1024 -> 32x16 = 512 blocks (r11 schedule, MH2=4)
  gemm8p<1,4><<<dim3(512), 512, 0, stream>>>(h, W1t, 1024, 4096, 16,
                                             b1, u, nullptr, nullptr, nullptr, nullptr);

  // MLP2: M=8192, N=1024, K=4096 -> BM=128: 64x4 = 256 blocks (triple-A, MH2=2)
  gemm8p<2,2><<<dim3(256), 512, 0, stream>>>(u, W2t, 4096, 1024, 4,
                                             b2, nullptr, out, nullptr, nullptr, nullptr);
}